// Round 5
// baseline (542.751 us; speedup 1.0000x reference)
//
#include <hip/hip_runtime.h>
#include <hip/hip_bf16.h>

// ---------------------------------------------------------------------------
// GAT x3 + fc + MLP. GEMMs bf16 MFMA (16x16x32). R5:
//  - gat_agg: batch-4 edge processing -> 4 independent h-row loads in flight
//    (memory-level parallelism; deg~4 means one batch per node typically).
//  - otherwise identical to R4 (no-max softmax, fused al epilogue, merged
//    weight conversions, all-MFMA MLP).
// ---------------------------------------------------------------------------

#define GAT_SLOPE 0.2f
#define ACT_SLOPE 0.01f

typedef unsigned short ushort_t;
typedef __attribute__((ext_vector_type(8))) short bf16x8;
typedef __attribute__((ext_vector_type(8))) unsigned short ushort8;
typedef __attribute__((ext_vector_type(4))) unsigned short ushort4v;
typedef __attribute__((ext_vector_type(4))) float floatx4;

__device__ __forceinline__ float lrelu(float x, float s) {
    return fmaxf(x, s * x);   // valid for 0<s<1
}

__device__ __forceinline__ ushort_t f2bf(float f) {
    union { float f; unsigned u; } x; x.f = f;
    unsigned r = x.u + 0x7FFF + ((x.u >> 16) & 1);   // round-nearest-even
    return (ushort_t)(r >> 16);
}

__device__ __forceinline__ float bf2f(ushort_t u) {
    union { unsigned u; float f; } x; x.u = ((unsigned)u) << 16;
    return x.f;
}

// ---------------- edge-index format probe ----------------
__global__ void detect_fmt(const int* __restrict__ raw, int nwords, int* flag) {
    __shared__ int nz;
    if (threadIdx.x == 0) nz = 0;
    __syncthreads();
    int lim = nwords < 4096 ? nwords : 4096;
    for (int i = threadIdx.x * 2 + 1; i < lim; i += 512)
        if (raw[i] != 0) atomicAdd(&nz, 1);
    __syncthreads();
    if (threadIdx.x == 0) *flag = (nz == 0) ? 1 : 0;   // 1 => int64 storage
}

__global__ void zero2(int* __restrict__ a, int* __restrict__ b, int n) {
    int i = blockIdx.x * blockDim.x + threadIdx.x;
    if (i < n) { a[i] = 0; b[i] = 0; }
}

// convert both halves + count dst in one pass
__global__ void convert_count(const int* __restrict__ raw, int E,
                              const int* __restrict__ flag,
                              int* __restrict__ idx32, int* __restrict__ counts) {
    int i = blockIdx.x * blockDim.x + threadIdx.x;
    if (i >= E) return;
    int f = *flag;
    int s = f ? raw[2 * i] : raw[i];
    int d = f ? raw[2 * (E + i)] : raw[E + i];
    idx32[i] = s;
    idx32[E + i] = d;
    atomicAdd(&counts[d], 1);
}

__global__ void scan_block(const int* __restrict__ counts, int* __restrict__ inc,
                           int* __restrict__ blockSums, int N) {
    __shared__ int sh[256];
    int i = blockIdx.x * 256 + threadIdx.x;
    int v = (i < N) ? counts[i] : 0;
    sh[threadIdx.x] = v;
    __syncthreads();
    for (int off = 1; off < 256; off <<= 1) {
        int t = (threadIdx.x >= off) ? sh[threadIdx.x - off] : 0;
        __syncthreads();
        sh[threadIdx.x] += t;
        __syncthreads();
    }
    if (i < N) inc[i] = sh[threadIdx.x];
    if (threadIdx.x == 255) blockSums[blockIdx.x] = sh[255];
}

__global__ void scan_sums(int* __restrict__ blockSums, int nb, int* __restrict__ row_ptr) {
    __shared__ int sh[512];
    int v = ((int)threadIdx.x < nb) ? blockSums[threadIdx.x] : 0;
    sh[threadIdx.x] = v;
    __syncthreads();
    for (int off = 1; off < 512; off <<= 1) {
        int t = (threadIdx.x >= off) ? sh[threadIdx.x - off] : 0;
        __syncthreads();
        sh[threadIdx.x] += t;
        __syncthreads();
    }
    if ((int)threadIdx.x < nb) blockSums[threadIdx.x] = sh[threadIdx.x];
    if (threadIdx.x == 0) row_ptr[0] = 0;
}

__global__ void scan_add(const int* __restrict__ inc, const int* __restrict__ blockSums,
                         int* __restrict__ row_ptr, int N) {
    int i = blockIdx.x * 256 + threadIdx.x;
    if (i < N) row_ptr[i + 1] = inc[i] + (blockIdx.x > 0 ? blockSums[blockIdx.x - 1] : 0);
}

__global__ void edge_fill(const int* __restrict__ src, const int* __restrict__ dst, int E,
                          const int* __restrict__ row_ptr, int* __restrict__ cursor,
                          int* __restrict__ col) {
    int i = blockIdx.x * blockDim.x + threadIdx.x;
    if (i < E) {
        int d = dst[i];
        int pos = row_ptr[d] + atomicAdd(&cursor[d], 1);
        col[pos] = src[i];
    }
}

// ---------------- conversions ----------------
__global__ void convert_bf4(const float* __restrict__ in, ushort_t* __restrict__ out, int n4) {
    int i = blockIdx.x * blockDim.x + threadIdx.x;
    if (i >= n4) return;
    const float4 v = ((const float4*)in)[i];
    ushort4v o;
    o.x = f2bf(v.x); o.y = f2bf(v.y); o.z = f2bf(v.z); o.w = f2bf(v.w);
    ((ushort4v*)out)[i] = o;
}

// pad-convert rows: in [M][Kr] fp32 -> out [M][Kp] bf16, cols >= Kr zeroed
__global__ void convert_padrow(const float* __restrict__ in, ushort_t* __restrict__ out,
                               int M, int Kr, int Kp) {
    int i = blockIdx.x * blockDim.x + threadIdx.x;
    if (i >= M * Kp) return;
    int r = i / Kp, c = i - r * Kp;
    out[i] = f2bf((c < Kr) ? in[(size_t)r * Kr + c] : 0.f);
}

// merged weight transposes: in [Kr,N] fp32 -> out [Npad,Kp] bf16
struct WConv { const float* in; ushort_t* out; int Kp, Kr, N, Npad, blkOff; };
struct WConvArr { WConv e[7]; int n; };

__global__ void convert_w_multi(WConvArr a) {
    int b = blockIdx.x;
    int ei = 0;
    for (int k = 1; k < a.n; k++)
        if (b >= a.e[k].blkOff) ei = k;
    WConv w = a.e[ei];
    int i = (b - w.blkOff) * 256 + threadIdx.x;
    if (i >= w.Npad * w.Kp) return;
    int n = i / w.Kp, k = i - n * w.Kp;
    float v = (n < w.N && k < w.Kr) ? w.in[(size_t)k * w.N + n] : 0.f;
    w.out[i] = f2bf(v);
}

#define LDA 40   // padded LDS row (elements): row stride 80B -> 2-way bank alias only

// ---------------- fused GAT GEMM: H_bf16 = A @ W ; al_s/al_d from fp32 acc ----
__global__ __launch_bounds__(256) void gemm_mfma_gat(
    const ushort_t* __restrict__ A, const ushort_t* __restrict__ Bt,
    const float* __restrict__ a_src, const float* __restrict__ a_dst,
    ushort_t* __restrict__ Hbf, float* __restrict__ al_s, float* __restrict__ al_d,
    int M, int K) {
    const int NCOL = 256;
    __shared__ __align__(16) ushort_t As[128 * LDA];
    __shared__ __align__(16) ushort_t Bs[128 * LDA];
    int t = threadIdx.x;
    int wave = t >> 6, lane = t & 63;
    int wm = (wave >> 1) << 6;
    int wn = (wave & 1) << 6;
    int rowBase = blockIdx.y << 7;
    int colBase = blockIdx.x << 7;
    int lrow = lane & 15, lquad = lane >> 4;
    floatx4 acc[4][4];
#pragma unroll
    for (int i = 0; i < 4; i++)
#pragma unroll
        for (int j = 0; j < 4; j++) acc[i][j] = (floatx4){0.f, 0.f, 0.f, 0.f};

    int srow = t >> 2;
    int sko  = (t & 3) * 8;
    const ushort8 zero8 = {0, 0, 0, 0, 0, 0, 0, 0};

    for (int k0 = 0; k0 < K; k0 += 32) {
        bool kin = (k0 + sko + 8) <= K;
#pragma unroll
        for (int half = 0; half < 2; half++) {
            int row = srow + half * 64;
            ushort8 va = kin ? *(const ushort8*)(A + (size_t)(rowBase + row) * K + k0 + sko)
                             : zero8;
            *(ushort8*)(As + row * LDA + sko) = va;
            ushort8 vb = kin ? *(const ushort8*)(Bt + (size_t)(colBase + row) * K + k0 + sko)
                             : zero8;
            *(ushort8*)(Bs + row * LDA + sko) = vb;
        }
        __syncthreads();
        bf16x8 af[4], bfv[4];
#pragma unroll
        for (int i = 0; i < 4; i++)
            af[i] = *(const bf16x8*)(As + (wm + i * 16 + lrow) * LDA + lquad * 8);
#pragma unroll
        for (int j = 0; j < 4; j++)
            bfv[j] = *(const bf16x8*)(Bs + (wn + j * 16 + lrow) * LDA + lquad * 8);
#pragma unroll
        for (int i = 0; i < 4; i++)
#pragma unroll
            for (int j = 0; j < 4; j++)
                acc[i][j] = __builtin_amdgcn_mfma_f32_16x16x32_bf16(af[i], bfv[j],
                                                                    acc[i][j], 0, 0, 0);
        __syncthreads();
    }
    int head = (colBase + wn) >> 6;
    float avs[4], avd[4];
#pragma unroll
    for (int j = 0; j < 4; j++) {
        avs[j] = a_src[head * 64 + j * 16 + lrow];
        avd[j] = a_dst[head * 64 + j * 16 + lrow];
    }
#pragma unroll
    for (int i = 0; i < 4; i++) {
#pragma unroll
        for (int r = 0; r < 4; r++) {
            float ps = 0.f, pd = 0.f;
#pragma unroll
            for (int j = 0; j < 4; j++) {
                ps += acc[i][j][r] * avs[j];
                pd += acc[i][j][r] * avd[j];
            }
#pragma unroll
            for (int off = 1; off < 16; off <<= 1) {
                ps += __shfl_xor(ps, off);
                pd += __shfl_xor(pd, off);
            }
            if (lrow == 0) {
                int gr = rowBase + wm + i * 16 + lquad * 4 + r;
                al_s[gr * 4 + head] = ps;
                al_d[gr * 4 + head] = pd;
            }
        }
        int grb = rowBase + wm + i * 16 + lquad * 4;
#pragma unroll
        for (int j = 0; j < 4; j++) {
            int gc = colBase + wn + j * 16 + lrow;
#pragma unroll
            for (int r = 0; r < 4; r++)
                Hbf[(size_t)(grb + r) * NCOL + gc] = f2bf(acc[i][j][r]);
        }
    }
}

// ---------------- bf16 MFMA GEMM (+bias, +lrelu), fp32 or bf16 out ----------
__global__ __launch_bounds__(256) void gemm_mfma(
    const ushort_t* __restrict__ A, const ushort_t* __restrict__ Bt,
    const float* __restrict__ bias, void* __restrict__ Cout,
    int M, int N, int K, int act, float slope, int outBf) {
    __shared__ __align__(16) ushort_t As[128 * LDA];
    __shared__ __align__(16) ushort_t Bs[128 * LDA];
    int t = threadIdx.x;
    int wave = t >> 6, lane = t & 63;
    int wm = (wave >> 1) << 6;
    int wn = (wave & 1) << 6;
    int rowBase = blockIdx.y << 7;
    int colBase = blockIdx.x << 7;
    int lrow = lane & 15, lquad = lane >> 4;
    floatx4 acc[4][4];
#pragma unroll
    for (int i = 0; i < 4; i++)
#pragma unroll
        for (int j = 0; j < 4; j++) acc[i][j] = (floatx4){0.f, 0.f, 0.f, 0.f};

    int srow = t >> 2;
    int sko  = (t & 3) * 8;
    const ushort8 zero8 = {0, 0, 0, 0, 0, 0, 0, 0};

    for (int k0 = 0; k0 < K; k0 += 32) {
        bool kin = (k0 + sko + 8) <= K;
#pragma unroll
        for (int half = 0; half < 2; half++) {
            int row = srow + half * 64;
            ushort8 va = kin ? *(const ushort8*)(A + (size_t)(rowBase + row) * K + k0 + sko)
                             : zero8;
            *(ushort8*)(As + row * LDA + sko) = va;
            ushort8 vb = kin ? *(const ushort8*)(Bt + (size_t)(colBase + row) * K + k0 + sko)
                             : zero8;
            *(ushort8*)(Bs + row * LDA + sko) = vb;
        }
        __syncthreads();
        bf16x8 af[4], bfv[4];
#pragma unroll
        for (int i = 0; i < 4; i++)
            af[i] = *(const bf16x8*)(As + (wm + i * 16 + lrow) * LDA + lquad * 8);
#pragma unroll
        for (int j = 0; j < 4; j++)
            bfv[j] = *(const bf16x8*)(Bs + (wn + j * 16 + lrow) * LDA + lquad * 8);
#pragma unroll
        for (int i = 0; i < 4; i++)
#pragma unroll
            for (int j = 0; j < 4; j++)
                acc[i][j] = __builtin_amdgcn_mfma_f32_16x16x32_bf16(af[i], bfv[j],
                                                                    acc[i][j], 0, 0, 0);
        __syncthreads();
    }
#pragma unroll
    for (int i = 0; i < 4; i++) {
        int gr = rowBase + wm + i * 16 + lquad * 4;
#pragma unroll
        for (int j = 0; j < 4; j++) {
            int gc = colBase + wn + j * 16 + lrow;
            if (gc >= N) continue;
            float b = bias ? bias[gc] : 0.f;
#pragma unroll
            for (int r = 0; r < 4; r++) {
                float v = acc[i][j][r] + b;
                if (act) v = lrelu(v, slope);
                if (outBf)
                    ((ushort_t*)Cout)[(size_t)(gr + r) * N + gc] = f2bf(v);
                else
                    ((float*)Cout)[(size_t)(gr + r) * N + gc] = v;
            }
        }
    }
}

// ---------------- aggregation: one wave per node, batch-4 gather ------------
__global__ __launch_bounds__(256) void gat_agg(
    const ushort_t* __restrict__ h_bf, const float* __restrict__ al_s,
    const float* __restrict__ al_d, const int* __restrict__ row_ptr,
    const int* __restrict__ col, const float* __restrict__ bias,
    ushort_t* __restrict__ out_bf, int N, int act, float slope) {
    int gw = __builtin_amdgcn_readfirstlane((blockIdx.x * 256 + threadIdx.x) >> 6);
    if (gw >= N) return;
    int lane = threadIdx.x & 63;
    int head = lane >> 4;
    int idx = gw * 4 + head;
    float ad = al_d[idx];
    const ushort4v* h4 = (const ushort4v*)h_bf;
    // self loop
    float p = __expf(lrelu(al_s[idx] + ad, GAT_SLOPE));
    ushort4v hv = h4[(size_t)gw * 64 + lane];
    float s = p;
    float4 acc;
    acc.x = p * bf2f(hv.x); acc.y = p * bf2f(hv.y);
    acc.z = p * bf2f(hv.z); acc.w = p * bf2f(hv.w);
    int beg = row_ptr[gw], end = row_ptr[gw + 1];
    for (int i = beg; i < end; i += 4) {
        int cnt = end - i;                 // wave-uniform
        // issue up to 4 col reads, then 4 independent row+al loads (MLP)
        int sn0 = col[i];
        int sn1 = (cnt > 1) ? col[i + 1] : sn0;
        int sn2 = (cnt > 2) ? col[i + 2] : sn0;
        int sn3 = (cnt > 3) ? col[i + 3] : sn0;
        ushort4v h0 = h4[(size_t)sn0 * 64 + lane];
        ushort4v h1 = h4[(size_t)sn1 * 64 + lane];
        ushort4v h2 = h4[(size_t)sn2 * 64 + lane];
        ushort4v h3 = h4[(size_t)sn3 * 64 + lane];
        float a0 = al_s[sn0 * 4 + head];
        float a1 = al_s[sn1 * 4 + head];
        float a2 = al_s[sn2 * 4 + head];
        float a3 = al_s[sn3 * 4 + head];
        float p0 = __expf(lrelu(a0 + ad, GAT_SLOPE));
        acc.x += p0 * bf2f(h0.x); acc.y += p0 * bf2f(h0.y);
        acc.z += p0 * bf2f(h0.z); acc.w += p0 * bf2f(h0.w);
        s += p0;
        if (cnt > 1) {
            float p1 = __expf(lrelu(a1 + ad, GAT_SLOPE));
            acc.x += p1 * bf2f(h1.x); acc.y += p1 * bf2f(h1.y);
            acc.z += p1 * bf2f(h1.z); acc.w += p1 * bf2f(h1.w);
            s += p1;
        }
        if (cnt > 2) {
            float p2 = __expf(lrelu(a2 + ad, GAT_SLOPE));
            acc.x += p2 * bf2f(h2.x); acc.y += p2 * bf2f(h2.y);
            acc.z += p2 * bf2f(h2.z); acc.w += p2 * bf2f(h2.w);
            s += p2;
        }
        if (cnt > 3) {
            float p3 = __expf(lrelu(a3 + ad, GAT_SLOPE));
            acc.x += p3 * bf2f(h3.x); acc.y += p3 * bf2f(h3.y);
            acc.z += p3 * bf2f(h3.z); acc.w += p3 * bf2f(h3.w);
            s += p3;
        }
    }
    float rs = 1.f / s;
    float4 bv = ((const float4*)bias)[lane];
    acc.x = acc.x * rs + bv.x; acc.y = acc.y * rs + bv.y;
    acc.z = acc.z * rs + bv.z; acc.w = acc.w * rs + bv.w;
    if (act) {
        acc.x = lrelu(acc.x, slope); acc.y = lrelu(acc.y, slope);
        acc.z = lrelu(acc.z, slope); acc.w = lrelu(acc.w, slope);
    }
    ushort4v o;
    o.x = f2bf(acc.x); o.y = f2bf(acc.y); o.z = f2bf(acc.z); o.w = f2bf(acc.w);
    ((ushort4v*)out_bf)[(size_t)gw * 64 + lane] = o;
}

// ---------------------------------------------------------------------------
extern "C" void kernel_launch(void* const* d_in, const int* in_sizes, int n_in,
                              void* d_out, int out_size, void* d_ws, size_t ws_size,
                              hipStream_t stream) {
    const float* x        = (const float*)d_in[0];
    const int*   rawEdge  = (const int*)d_in[1];
    const float* rootCtx  = (const float*)d_in[2];
    const float* W[3]     = {(const float*)d_in[3], (const float*)d_in[7], (const float*)d_in[11]};
    const float* aS[3]    = {(const float*)d_in[4], (const float*)d_in[8], (const float*)d_in[12]};
    const float* aD[3]    = {(const float*)d_in[5], (const float*)d_in[9], (const float*)d_in[13]};
    const float* bb[3]    = {(const float*)d_in[6], (const float*)d_in[10], (const float*)d_in[14]};
    const float* fc_w     = (const float*)d_in[15];
    const float* fc_b     = (const float*)d_in[16];
    const float* r_w1     = (const float*)d_in[17];
    const float* r_b1     = (const float*)d_in[18];
    const float* r_w2     = (const float*)d_in[19];
    const float* r_b2     = (const float*)d_in[20];
    const float* r_w3     = (const float*)d_in[21];
    const float* r_b3     = (const float*)d_in[22];

    const int N  = in_sizes[0] / 80;      // 102400
    const int E  = in_sizes[1] / 2;       // 409600
    const int R  = in_sizes[2] / 60;      // 4096
    const int N4 = N * 4;
    const int HC = 256;

    float* outRot  = (float*)d_out;                  // [N, 80]
    float* outRoot = (float*)d_out + (size_t)N * 80; // [R, 60]

    // ---- carve workspace ----
    size_t off = 0;
    auto carve = [&](size_t bytes) -> void* {
        off = (off + 255) & ~(size_t)255;
        void* p = (char*)d_ws + off;
        off += bytes;
        return p;
    };
    int*      flag      = (int*)carve(4);
    int*      idx32     = (int*)carve((size_t)2 * E * 4);
    int*      counts    = (int*)carve((size_t)N * 4);
    int*      cursor    = (int*)carve((size_t)N * 4);
    int*      row_ptr   = (int*)carve((size_t)(N + 1) * 4);
    int*      incArr    = (int*)carve((size_t)N * 4);
    int*      blockSums = (int*)carve(512 * 4);
    int*      colArr    = (int*)carve((size_t)E * 4);
    float*    al_s      = (float*)carve((size_t)N4 * 4);
    float*    al_d      = (float*)carve((size_t)N4 * 4);
    ushort_t* h_bf      = (ushort_t*)carve((size_t)N * HC * 2);
    ushort_t* agg_bf    = (ushort_t*)carve((size_t)N * HC * 2);
    ushort_t* x_bf      = (ushort_t*)carve((size_t)N * 80 * 2);
    ushort_t* rc_bf     = (ushort_t*)carve((size_t)R * 64 * 2);
    ushort_t* t1_bf     = (ushort_t*)carve((size_t)R * 512 * 2);
    ushort_t* t2_bf     = (ushort_t*)carve((size_t)R * 512 * 2);
    ushort_t* Wt0       = (ushort_t*)carve((size_t)256 * 80 * 2);
    ushort_t* Wt1       = (ushort_t*)carve((size_t)256 * 256 * 2);
    ushort_t* Wt2       = (ushort_t*)carve((size_t)256 * 256 * 2);
    ushort_t* fcWt      = (ushort_t*)carve((size_t)128 * 256 * 2);
    ushort_t* rW1t      = (ushort_t*)carve((size_t)512 * 64 * 2);
    ushort_t* rWt2      = (ushort_t*)carve((size_t)512 * 512 * 2);
    ushort_t* rWt3      = (ushort_t*)carve((size_t)128 * 512 * 2);

    const int nb = (N + 255) / 256;
    dim3 blk(256);

    // ---- edge format + CSR build ----
    detect_fmt<<<1, 256, 0, stream>>>(rawEdge, 2 * E, flag);
    zero2<<<(N + 255) / 256, blk, 0, stream>>>(counts, cursor, N);
    convert_count<<<(E + 255) / 256, blk, 0, stream>>>(rawEdge, E, flag, idx32, counts);
    const int* srcArr = idx32;
    const int* dstArr = idx32 + E;
    scan_block<<<nb, 256, 0, stream>>>(counts, incArr, blockSums, N);
    scan_sums<<<1, 512, 0, stream>>>(blockSums, nb, row_ptr);
    scan_add<<<nb, 256, 0, stream>>>(incArr, blockSums, row_ptr, N);
    edge_fill<<<(E + 255) / 256, blk, 0, stream>>>(srcArr, dstArr, E, row_ptr, cursor, colArr);

    // ---- weight conversions (merged) ----
    {
        WConvArr wa;
        auto mk = [&](int i, const float* in, ushort_t* out, int Kp, int Kr, int Nn, int Npad,
                      int blkOff) {
            wa.e[i] = WConv{in, out, Kp, Kr, Nn, Npad, blkOff};
        };
        int boff = 0;
        auto nblk = [](int Npad, int Kp) { return (Npad * Kp + 255) / 256; };
        mk(0, W[0], Wt0, 80, 80, 256, 256, boff);  boff += nblk(256, 80);
        mk(1, W[1], Wt1, 256, 256, 256, 256, boff); boff += nblk(256, 256);
        mk(2, W[2], Wt2, 256, 256, 256, 256, boff); boff += nblk(256, 256);
        mk(3, fc_w, fcWt, 256, 256, 80, 128, boff); boff += nblk(128, 256);
        mk(4, r_w1, rW1t, 64, 60, 512, 512, boff);  boff += nblk(512, 64);
        mk(5, r_w2, rWt2, 512, 512, 512, 512, boff); boff += nblk(512, 512);
        mk(6, r_w3, rWt3, 512, 512, 60, 128, boff);  boff += nblk(128, 512);
        wa.n = 7;
        convert_w_multi<<<boff, blk, 0, stream>>>(wa);
    }
    convert_bf4<<<(N * 80 / 4 + 255) / 256, blk, 0, stream>>>(x, x_bf, N * 80 / 4);
    convert_padrow<<<(R * 64 + 255) / 256, blk, 0, stream>>>(rootCtx, rc_bf, R, 60, 64);

    // ---- GAT layers ----
    const ushort_t* curA = x_bf;
    int curK = 80;
    for (int l = 0; l < 3; l++) {
        dim3 g1(2, N / 128);
        gemm_mfma_gat<<<g1, blk, 0, stream>>>(curA, l == 0 ? Wt0 : (l == 1 ? Wt1 : Wt2),
                                              aS[l], aD[l], h_bf, al_s, al_d, N, curK);
        int act = (l < 2) ? 1 : 0;
        gat_agg<<<(N * 64 + 255) / 256, blk, 0, stream>>>(h_bf, al_s, al_d, row_ptr,
                                                          colArr, bb[l], agg_bf, N,
                                                          act, ACT_SLOPE);
        curA = agg_bf;
        curK = HC;
    }

    // ---- rot = h @ fc_w + fc_b ----
    {
        dim3 g(1, N / 128);
        gemm_mfma<<<g, blk, 0, stream>>>(agg_bf, fcWt, fc_b, outRot, N, 80, HC, 0, 0.f, 0);
    }
    // ---- MLP branch (all MFMA, bf16 chaining) ----
    {
        dim3 g1(512 / 128, R / 128);
        gemm_mfma<<<g1, blk, 0, stream>>>(rc_bf, rW1t, r_b1, t1_bf, R, 512, 64,
                                          1, ACT_SLOPE, 1);
        dim3 g2(512 / 128, R / 128);
        gemm_mfma<<<g2, blk, 0, stream>>>(t1_bf, rWt2, r_b2, t2_bf, R, 512, 512,
                                          1, ACT_SLOPE, 1);
        dim3 g3(1, R / 128);
        gemm_mfma<<<g3, blk, 0, stream>>>(t2_bf, rWt3, r_b3, outRoot, R, 60, 512,
                                          0, 0.f, 0);
    }
}